// Round 2
// baseline (5976.323 us; speedup 1.0000x reference)
//
#include <hip/hip_runtime.h>

#define N_NODES 131072
#define IN_DIM  256
#define HID     512
#define NOUT    1024
#define N_GRAPHS 256
#define N_EDGES  2097152

#define BM 32
#define BK 16
#define TOPK_CAP 4096

// ---------------- segment starts via binary search ----------------
__global__ void k_starts(const int* __restrict__ batch, int* __restrict__ starts) {
    int g = blockIdx.x * blockDim.x + threadIdx.x;
    if (g > N_GRAPHS) return;
    int lo = 0, hi = N_NODES;
    while (lo < hi) {
        int mid = (lo + hi) >> 1;
        if (batch[mid] < g) lo = mid + 1; else hi = mid;
    }
    starts[g] = lo;  // first index with batch[idx] >= g ; starts[256] = N
}

// ---------------- fused head: GEMM + bias + LN + ReLU + GEMV + sigmoid ----------------
// block: 256 threads, tile = BM(32) nodes x 1024 cols, K-step BK=16
// thread (tr = tid/64 = wave, tc = tid%64): nodes tr*8..tr*8+7, cols {q*256 + tc*4 + j}
// fp32 vector-ALU GEMM on purpose: no fp32 MFMA on CDNA4, and bf16 downcast
// risks flipping the per-graph top-k boundary (min gap ~1e-6 over 256 graphs).
__global__ __launch_bounds__(256, 2) void k_head(
    const float* __restrict__ h, const float* __restrict__ W1,
    const float* __restrict__ b1, const float* __restrict__ gamma,
    const float* __restrict__ beta, const float* __restrict__ W2,
    const float* __restrict__ b2, float* __restrict__ logits)
{
    __shared__ __align__(16) float W1s[BK * NOUT];   // 64 KB
    __shared__ __align__(16) float hs[BK][BM];       // 2 KB, transposed h tile

    const int tid = threadIdx.x;
    const int tc  = tid & 63;
    const int tr  = tid >> 6;
    const int tc4 = tc * 4;
    const int node0 = blockIdx.x * BM;

    float acc[8][16];
#pragma unroll
    for (int m = 0; m < 8; ++m)
#pragma unroll
        for (int n = 0; n < 16; ++n) acc[m][n] = 0.f;

#pragma unroll 1   // keep I$ small: body has ~2k FMAs already
    for (int kt = 0; kt < HID / BK; ++kt) {
        __syncthreads();
        // stage h tile (32 nodes x 16 k), transposed into hs[k][node]
        if (tid < 128) {
            const int node = tid >> 2;
            const int k4   = (tid & 3) * 4;
            const float4 v = *reinterpret_cast<const float4*>(
                &h[(size_t)(node0 + node) * HID + kt * BK + k4]);
            hs[k4 + 0][node] = v.x; hs[k4 + 1][node] = v.y;
            hs[k4 + 2][node] = v.z; hs[k4 + 3][node] = v.w;
        }
        // stage W1 tile (16 x 1024), linear copy (1.5% of inner-loop instrs)
        const float* w1p = W1 + (size_t)kt * BK * NOUT;
#pragma unroll 4
        for (int r = 0; r < 16; ++r) {
            const int idx = r * 256 + tid;        // float4 index 0..4095
            *reinterpret_cast<float4*>(&W1s[idx * 4]) =
                *reinterpret_cast<const float4*>(&w1p[idx * 4]);
        }
        __syncthreads();
#pragma unroll
        for (int k = 0; k < BK; ++k) {
            // hs reads are wave-uniform (depend on tr only) -> LDS broadcast
            const float4 a0 = *reinterpret_cast<const float4*>(&hs[k][tr * 8]);
            const float4 a1 = *reinterpret_cast<const float4*>(&hs[k][tr * 8 + 4]);
            const float a[8] = {a0.x, a0.y, a0.z, a0.w, a1.x, a1.y, a1.z, a1.w};
#pragma unroll
            for (int q = 0; q < 4; ++q) {
                const float4 b = *reinterpret_cast<const float4*>(
                    &W1s[k * NOUT + q * 256 + tc4]);
#pragma unroll
                for (int m = 0; m < 8; ++m) {
                    acc[m][q * 4 + 0] += a[m] * b.x;
                    acc[m][q * 4 + 1] += a[m] * b.y;
                    acc[m][q * 4 + 2] += a[m] * b.z;
                    acc[m][q * 4 + 3] += a[m] * b.w;
                }
            }
        }
    }

    // epilogue: + b1, LayerNorm, ReLU, dot W2, + b2, sigmoid
    float b1v[16], gav[16], bev[16], w2v[16];
#pragma unroll
    for (int q = 0; q < 4; ++q) {
        const float4 bb = *reinterpret_cast<const float4*>(&b1[q * 256 + tc4]);
        const float4 gg = *reinterpret_cast<const float4*>(&gamma[q * 256 + tc4]);
        const float4 ee = *reinterpret_cast<const float4*>(&beta[q * 256 + tc4]);
        const float4 ww = *reinterpret_cast<const float4*>(&W2[q * 256 + tc4]);
        b1v[q*4+0]=bb.x; b1v[q*4+1]=bb.y; b1v[q*4+2]=bb.z; b1v[q*4+3]=bb.w;
        gav[q*4+0]=gg.x; gav[q*4+1]=gg.y; gav[q*4+2]=gg.z; gav[q*4+3]=gg.w;
        bev[q*4+0]=ee.x; bev[q*4+1]=ee.y; bev[q*4+2]=ee.z; bev[q*4+3]=ee.w;
        w2v[q*4+0]=ww.x; w2v[q*4+1]=ww.y; w2v[q*4+2]=ww.z; w2v[q*4+3]=ww.w;
    }
    const float b2v = b2[0];
#pragma unroll
    for (int m = 0; m < 8; ++m)
#pragma unroll
        for (int n = 0; n < 16; ++n) acc[m][n] += b1v[n];

    const float inv = 1.0f / (float)NOUT;
#pragma unroll
    for (int m = 0; m < 8; ++m) {
        float s = 0.f, ss = 0.f;
#pragma unroll
        for (int n = 0; n < 16; ++n) { const float v = acc[m][n]; s += v; ss += v * v; }
#pragma unroll
        for (int off = 32; off >= 1; off >>= 1) {
            s  += __shfl_xor(s, off);
            ss += __shfl_xor(ss, off);
        }
        const float mu = s * inv;
        float var = ss * inv - mu * mu;
        if (var < 0.f) var = 0.f;
        const float rstd = 1.0f / sqrtf(var + 1e-5f);
        float u = 0.f;
#pragma unroll
        for (int n = 0; n < 16; ++n) {
            float zn = (acc[m][n] - mu) * rstd * gav[n] + bev[n];
            zn = fmaxf(zn, 0.f);
            u += zn * w2v[n];
        }
#pragma unroll
        for (int off = 32; off >= 1; off >>= 1) u += __shfl_xor(u, off);
        if (tc == 0) {
            u += b2v;
            logits[node0 + tr * 8 + m] = 1.0f / (1.0f + expf(-u));
        }
    }
}

// ---------------- per-graph top-k + x_new ----------------
// one block per graph; rank by counting (matches stable lexsort:
// logit desc, original index asc on ties). Graphs avg 512 nodes (max ~650).
__global__ void k_topk(const float* __restrict__ logits, const int* __restrict__ starts,
                       const float* __restrict__ x, const float* __restrict__ noise,
                       float* __restrict__ xnew)
{
    __shared__ float ls[TOPK_CAP];
    __shared__ int   lk[TOPK_CAP];
    const int g  = blockIdx.x;
    const int s0 = starts[g], s1 = starts[g + 1];
    const int n  = s1 - s0;
    if (n <= 0) return;
    const int t = threadIdx.x;
    for (int i = t; i < n && i < TOPK_CAP; i += 256) ls[i] = logits[s0 + i];
    __syncthreads();
    const int k = (9 * n + 9) / 10;  // ceil(0.9*n)
    for (int i = t; i < n && i < TOPK_CAP; i += 256) {
        const float li = ls[i];
        int rank = 0;
        for (int j = 0; j < n; ++j) {
            const float lj = (j < TOPK_CAP) ? ls[j] : logits[s0 + j];
            rank += (lj > li) || (lj == li && j < i);
        }
        lk[i] = (rank < k) ? 1 : 0;
    }
    __syncthreads();
    // cooperative row writes: 4 rows at a time, 64 lanes x float4 per row
    const int sub = t >> 6;
    const int c4  = (t & 63) * 4;
    for (int i0 = 0; i0 < n; i0 += 4) {
        const int i = i0 + sub;
        if (i < n) {
            const size_t row = (size_t)(s0 + i) * IN_DIM;
            float4 o;
            if (i < TOPK_CAP && lk[i]) {
                const float li = ls[i];
                const float4 xv = *reinterpret_cast<const float4*>(&x[row + c4]);
                o.x = xv.x * li; o.y = xv.y * li; o.z = xv.z * li; o.w = xv.w * li;
            } else {
                o = *reinterpret_cast<const float4*>(&noise[row + c4]);
            }
            *reinterpret_cast<float4*>(&xnew[row + c4]) = o;
        }
    }
}

// ---------------- edge mask ----------------
__global__ void k_zero(float* __restrict__ em) {
    const int i = blockIdx.x * blockDim.x + threadIdx.x;
    if (i < N_NODES) em[i] = 0.f;
}
__global__ void k_scatter(const int* __restrict__ ei, float* __restrict__ em) {
    for (int i = blockIdx.x * blockDim.x + threadIdx.x; i < 2 * N_EDGES;
         i += gridDim.x * blockDim.x)
        em[ei[i]] = 1.0f;  // racing same-value stores are benign
}

extern "C" void kernel_launch(void* const* d_in, const int* in_sizes, int n_in,
                              void* d_out, int out_size, void* d_ws, size_t ws_size,
                              hipStream_t stream)
{
    const float* h     = (const float*)d_in[0];
    const float* x     = (const float*)d_in[1];
    const float* noise = (const float*)d_in[2];
    const float* W1    = (const float*)d_in[3];
    const float* b1    = (const float*)d_in[4];
    const float* gamma = (const float*)d_in[5];
    const float* beta  = (const float*)d_in[6];
    const float* W2    = (const float*)d_in[7];
    const float* b2    = (const float*)d_in[8];
    const int* batch   = (const int*)d_in[9];
    const int* eidx    = (const int*)d_in[10];

    float* xnew   = (float*)d_out;                       // [131072, 256]
    float* logits = xnew + (size_t)N_NODES * IN_DIM;     // [131072]
    float* emask  = logits + N_NODES;                    // [131072] (bool as 0/1 float)
    int*   starts = (int*)d_ws;                          // [257]

    hipLaunchKernelGGL(k_starts, dim3(2), dim3(160), 0, stream, batch, starts);
    hipLaunchKernelGGL(k_head, dim3(N_NODES / BM), dim3(256), 0, stream,
                       h, W1, b1, gamma, beta, W2, b2, logits);
    hipLaunchKernelGGL(k_zero, dim3((N_NODES + 255) / 256), dim3(256), 0, stream, emask);
    hipLaunchKernelGGL(k_scatter, dim3(2048), dim3(256), 0, stream, eidx, emask);
    hipLaunchKernelGGL(k_topk, dim3(N_GRAPHS), dim3(256), 0, stream,
                       logits, starts, x, noise, xnew);
}

// Round 4
// 4050.384 us; speedup vs baseline: 1.4755x; 1.4755x over previous
//
#include <hip/hip_runtime.h>

#define N_NODES 131072
#define IN_DIM  256
#define HID     512
#define NOUT    1024
#define N_GRAPHS 256
#define N_EDGES  2097152

#define BM 32
#define BK 16
#define TOPK_CAP 4096

// ---------------- segment starts via binary search ----------------
__global__ void k_starts(const int* __restrict__ batch, int* __restrict__ starts) {
    int g = blockIdx.x * blockDim.x + threadIdx.x;
    if (g > N_GRAPHS) return;
    int lo = 0, hi = N_NODES;
    while (lo < hi) {
        int mid = (lo + hi) >> 1;
        if (batch[mid] < g) lo = mid + 1; else hi = mid;
    }
    starts[g] = lo;  // first index with batch[idx] >= g ; starts[256] = N
}

// ---------------- fused head: GEMM + bias + LN + ReLU + GEMV + sigmoid ----------------
// 512 threads (8 waves). Block tile 32 nodes x 1024 cols, K-step 16.
// wave w: wr=w>>1 -> nodes wr*8..wr*8+7 ; wc=w&1 -> col half wc*512.
// thread: 8 nodes x 8 cols (cols wc*512 + q*256 + lane*4 + j, q=0..1).
// acc = 64 VGPRs (round-2 kernel had 128 -> spilled -> 18 GB scratch traffic @3.1TB/s).
__global__ __launch_bounds__(512, 4) void k_head(
    const float* __restrict__ h, const float* __restrict__ W1,
    const float* __restrict__ b1, const float* __restrict__ gamma,
    const float* __restrict__ beta, const float* __restrict__ W2,
    const float* __restrict__ b2, float* __restrict__ logits)
{
    __shared__ __align__(16) float W1s[BK * NOUT];   // 64 KB
    __shared__ __align__(16) float hs[BK][BM];       // 2 KB (transposed h tile)
    __shared__ float redS[BM][2], redSS[BM][2], redU[BM][2];  // LN cross-wave scratch

    const int tid  = threadIdx.x;
    const int lane = tid & 63;
    const int w    = tid >> 6;      // 0..7
    const int wr   = w >> 1;        // node group 0..3
    const int wc   = w & 1;         // col half 0..1
    const int col0 = wc * 512 + lane * 4;   // + q*256
    const int node0 = blockIdx.x * BM;

    float acc[8][2][4];
#pragma unroll
    for (int m = 0; m < 8; ++m)
#pragma unroll
        for (int q = 0; q < 2; ++q)
#pragma unroll
            for (int j = 0; j < 4; ++j) acc[m][q][j] = 0.f;

#pragma unroll 1   // keep I$ small
    for (int kt = 0; kt < HID / BK; ++kt) {
        __syncthreads();
        // stage h tile (32 nodes x 16 k) transposed
        if (tid < 128) {
            const int node = tid >> 2;
            const int k4   = (tid & 3) * 4;
            const float4 v = *reinterpret_cast<const float4*>(
                &h[(size_t)(node0 + node) * HID + kt * BK + k4]);
            hs[k4 + 0][node] = v.x; hs[k4 + 1][node] = v.y;
            hs[k4 + 2][node] = v.z; hs[k4 + 3][node] = v.w;
        }
        // stage W1 tile (16 x 1024 = 4096 float4s), linear
        const float4* w1p = reinterpret_cast<const float4*>(W1 + (size_t)kt * BK * NOUT);
        float4* w1s = reinterpret_cast<float4*>(W1s);
#pragma unroll
        for (int i = 0; i < 8; ++i) w1s[i * 512 + tid] = w1p[i * 512 + tid];
        __syncthreads();

#pragma unroll
        for (int k = 0; k < BK; ++k) {
            // wave-uniform (broadcast) reads of the 8 node values
            const float4 a0 = *reinterpret_cast<const float4*>(&hs[k][wr * 8]);
            const float4 a1 = *reinterpret_cast<const float4*>(&hs[k][wr * 8 + 4]);
            const float a[8] = {a0.x, a0.y, a0.z, a0.w, a1.x, a1.y, a1.z, a1.w};
            const float4 bA = *reinterpret_cast<const float4*>(&W1s[k * NOUT + col0]);
            const float4 bB = *reinterpret_cast<const float4*>(&W1s[k * NOUT + col0 + 256]);
#pragma unroll
            for (int m = 0; m < 8; ++m) {
                acc[m][0][0] += a[m] * bA.x; acc[m][0][1] += a[m] * bA.y;
                acc[m][0][2] += a[m] * bA.z; acc[m][0][3] += a[m] * bA.w;
                acc[m][1][0] += a[m] * bB.x; acc[m][1][1] += a[m] * bB.y;
                acc[m][1][2] += a[m] * bB.z; acc[m][1][3] += a[m] * bB.w;
            }
        }
    }

    // ---- epilogue: + b1, LayerNorm over 1024 (split across wave pair), ReLU, dot W2 ----
    float b1v[2][4], gav[2][4], bev[2][4], w2v[2][4];
#pragma unroll
    for (int q = 0; q < 2; ++q) {
        const int c = col0 + q * 256;
        const float4 bb = *reinterpret_cast<const float4*>(&b1[c]);
        const float4 gg = *reinterpret_cast<const float4*>(&gamma[c]);
        const float4 ee = *reinterpret_cast<const float4*>(&beta[c]);
        const float4 ww = *reinterpret_cast<const float4*>(&W2[c]);
        b1v[q][0]=bb.x; b1v[q][1]=bb.y; b1v[q][2]=bb.z; b1v[q][3]=bb.w;
        gav[q][0]=gg.x; gav[q][1]=gg.y; gav[q][2]=gg.z; gav[q][3]=gg.w;
        bev[q][0]=ee.x; bev[q][1]=ee.y; bev[q][2]=ee.z; bev[q][3]=ee.w;
        w2v[q][0]=ww.x; w2v[q][1]=ww.y; w2v[q][2]=ww.z; w2v[q][3]=ww.w;
    }

#pragma unroll
    for (int m = 0; m < 8; ++m) {
        float s = 0.f, ss = 0.f;
#pragma unroll
        for (int q = 0; q < 2; ++q)
#pragma unroll
            for (int j = 0; j < 4; ++j) {
                const float v = acc[m][q][j] + b1v[q][j];
                acc[m][q][j] = v;
                s += v; ss += v * v;
            }
#pragma unroll
        for (int off = 32; off >= 1; off >>= 1) {
            s  += __shfl_xor(s, off);
            ss += __shfl_xor(ss, off);
        }
        if (lane == 0) { redS[wr * 8 + m][wc] = s; redSS[wr * 8 + m][wc] = ss; }
    }
    __syncthreads();

    const float inv = 1.0f / (float)NOUT;
#pragma unroll
    for (int m = 0; m < 8; ++m) {
        const int node = wr * 8 + m;
        const float s  = redS[node][0]  + redS[node][1];
        const float ss = redSS[node][0] + redSS[node][1];
        const float mu = s * inv;
        float var = ss * inv - mu * mu;
        if (var < 0.f) var = 0.f;
        const float rstd = 1.0f / sqrtf(var + 1e-5f);
        float u = 0.f;
#pragma unroll
        for (int q = 0; q < 2; ++q)
#pragma unroll
            for (int j = 0; j < 4; ++j) {
                float zn = (acc[m][q][j] - mu) * rstd * gav[q][j] + bev[q][j];
                zn = fmaxf(zn, 0.f);
                u += zn * w2v[q][j];
            }
#pragma unroll
        for (int off = 32; off >= 1; off >>= 1) u += __shfl_xor(u, off);
        if (lane == 0) redU[node][wc] = u;
    }
    __syncthreads();

    if (tid < BM) {
        const float u = redU[tid][0] + redU[tid][1] + b2[0];
        logits[node0 + tid] = 1.0f / (1.0f + expf(-u));
    }
}

// ---------------- per-graph top-k + x_new ----------------
// one block per graph; rank by counting (matches stable lexsort:
// logit desc, original index asc on ties). Graphs avg 512 nodes.
__global__ void k_topk(const float* __restrict__ logits, const int* __restrict__ starts,
                       const float* __restrict__ x, const float* __restrict__ noise,
                       float* __restrict__ xnew)
{
    __shared__ float ls[TOPK_CAP];
    __shared__ int   lk[TOPK_CAP];
    const int g  = blockIdx.x;
    const int s0 = starts[g], s1 = starts[g + 1];
    const int n  = s1 - s0;
    if (n <= 0) return;
    const int t = threadIdx.x;
    for (int i = t; i < n && i < TOPK_CAP; i += 256) ls[i] = logits[s0 + i];
    __syncthreads();
    const int k = (9 * n + 9) / 10;  // ceil(0.9*n)
    for (int i = t; i < n && i < TOPK_CAP; i += 256) {
        const float li = ls[i];
        int rank = 0;
        for (int j = 0; j < n; ++j) {
            const float lj = (j < TOPK_CAP) ? ls[j] : logits[s0 + j];
            rank += (lj > li) || (lj == li && j < i);
        }
        lk[i] = (rank < k) ? 1 : 0;
    }
    __syncthreads();
    const int sub = t >> 6;
    const int c4  = (t & 63) * 4;
    for (int i0 = 0; i0 < n; i0 += 4) {
        const int i = i0 + sub;
        if (i < n) {
            const size_t row = (size_t)(s0 + i) * IN_DIM;
            float4 o;
            if (i < TOPK_CAP && lk[i]) {
                const float li = ls[i];
                const float4 xv = *reinterpret_cast<const float4*>(&x[row + c4]);
                o.x = xv.x * li; o.y = xv.y * li; o.z = xv.z * li; o.w = xv.w * li;
            } else {
                o = *reinterpret_cast<const float4*>(&noise[row + c4]);
            }
            *reinterpret_cast<float4*>(&xnew[row + c4]) = o;
        }
    }
}

// ---------------- edge mask ----------------
__global__ void k_zero(float* __restrict__ em) {
    const int i = blockIdx.x * blockDim.x + threadIdx.x;
    if (i < N_NODES) em[i] = 0.f;
}
__global__ void k_scatter(const int* __restrict__ ei, float* __restrict__ em) {
    for (int i = blockIdx.x * blockDim.x + threadIdx.x; i < 2 * N_EDGES;
         i += gridDim.x * blockDim.x)
        em[ei[i]] = 1.0f;  // racing same-value stores are benign
}

extern "C" void kernel_launch(void* const* d_in, const int* in_sizes, int n_in,
                              void* d_out, int out_size, void* d_ws, size_t ws_size,
                              hipStream_t stream)
{
    const float* h     = (const float*)d_in[0];
    const float* x     = (const float*)d_in[1];
    const float* noise = (const float*)d_in[2];
    const float* W1    = (const float*)d_in[3];
    const float* b1    = (const float*)d_in[4];
    const float* gamma = (const float*)d_in[5];
    const float* beta  = (const float*)d_in[6];
    const float* W2    = (const float*)d_in[7];
    const float* b2    = (const float*)d_in[8];
    const int* batch   = (const int*)d_in[9];
    const int* eidx    = (const int*)d_in[10];

    float* xnew   = (float*)d_out;                       // [131072, 256]
    float* logits = xnew + (size_t)N_NODES * IN_DIM;     // [131072]
    float* emask  = logits + N_NODES;                    // [131072] (bool as 0/1)
    int*   starts = (int*)d_ws;                          // [257]

    hipLaunchKernelGGL(k_starts, dim3(2), dim3(160), 0, stream, batch, starts);
    hipLaunchKernelGGL(k_head, dim3(N_NODES / BM), dim3(512), 0, stream,
                       h, W1, b1, gamma, beta, W2, b2, logits);
    hipLaunchKernelGGL(k_zero, dim3((N_NODES + 255) / 256), dim3(256), 0, stream, emask);
    hipLaunchKernelGGL(k_scatter, dim3(2048), dim3(256), 0, stream, eidx, emask);
    hipLaunchKernelGGL(k_topk, dim3(N_GRAPHS), dim3(256), 0, stream,
                       logits, starts, x, noise, xnew);
}